// Round 5
// baseline (68.409 us; speedup 1.0000x reference)
//
#include <hip/hip_runtime.h>
#include <math.h>

#define BLOCK 256
#define SPLIT 4            // threads cooperating per pixel-pair
#define PPT   2            // pixels per thread, packed into v2f lanes
#define MAX_KV_LDS 1024    // vertex cap for LDS staging (+1 duplicate slot)

typedef float v2f __attribute__((ext_vector_type(2)));

__device__ __forceinline__ float rcp1(float x) { return __builtin_amdgcn_rcpf(x); }

// term(cross, dot) = tanh(1e5*cross) * atan2(|cross|, dot), packed 2-wide.
// atan2(|c|,d) == acos(d / (|diff||roll|)) -- no norms, no rsq, no sqrt.
__device__ __forceinline__ v2f edge_term(v2f cross, v2f dot)
{
    // tanh(1e5*x) via Pade(5,4): x(945+105x^2+x^4)/(945+420x^2+15x^4), clamp +-1
    v2f t = cross * 100000.0f;
    v2f s = t * t;
    v2f pn = (s + 105.0f) * s + 945.0f;
    v2f num = t * pn;
    v2f qd = (15.0f * s + 420.0f) * s + 945.0f;
    v2f th;
    th.x = __builtin_amdgcn_fmed3f(num.x * rcp1(qd.x), -1.0f, 1.0f);
    th.y = __builtin_amdgcn_fmed3f(num.y * rcp1(qd.y), -1.0f, 1.0f);

    // angle = atan2(|cross|, dot) in [0, pi]; Hastings poly, err ~1e-5
    v2f ac = { fabsf(cross.x), fabsf(cross.y) };
    v2f ad = { fabsf(dot.x),   fabsf(dot.y)   };
    v2f mn = { fminf(ac.x, ad.x), fminf(ac.y, ad.y) };
    v2f mx = { fmaxf(ac.x, ad.x), fmaxf(ac.y, ad.y) };
    v2f a  = { mn.x * rcp1(mx.x), mn.y * rcp1(mx.y) };
    v2f s2 = a * a;
    v2f r = 0.0208351f * s2 - 0.0851330f;
    r = r * s2 + 0.1801410f;
    r = r * s2 - 0.3302995f;
    r = r * s2 + 0.9998660f;
    r = r * a;
    v2f rhi = 1.57079632679f - r;          // octant fold: |cross| > |dot|
    r.x = (ac.x > ad.x) ? rhi.x : r.x;
    r.y = (ac.y > ad.y) ? rhi.y : r.y;
    v2f rneg = 3.14159265359f - r;         // dot < 0 half-plane
    r.x = (dot.x < 0.0f) ? rneg.x : r.x;
    r.y = (dot.y < 0.0f) ? rneg.y : r.y;

    return th * r;
}

// packed 2-pixel winding partial over edges [k0,k1); verts[kv] duplicates
// verts[0] so the loop has no wraparound select.
__device__ __forceinline__ v2f winding_pk(const float2* __restrict__ verts,
                                          int k0, int k1, v2f mx2, v2f my2)
{
    v2f acc = {0.0f, 0.0f};
    if (k0 >= k1) return acc;
    float2 v = verts[k0];
    v2f dx = v.x - mx2, dy = v.y - my2;

    #pragma unroll 4
    for (int k = k0; k < k1; ++k) {
        float2 vn = verts[k + 1];          // duplicate slot handles wrap
        v2f rx = vn.x - mx2, ry = vn.y - my2;
        v2f cross = dy * rx - dx * ry;     // matches reference sign
        v2f dot   = dx * rx + dy * ry;
        acc = acc + edge_term(cross, dot);
        dx = rx; dy = ry;
    }
    return acc;
}

// cold scalar fallback (blocks straddling an image boundary)
__device__ __forceinline__ float winding_scalar(const float2* __restrict__ vsrc,
                                                int kv, int k0, int k1,
                                                float mxs, float mys)
{
    float acc = 0.0f;
    if (k0 >= k1) return acc;
    float2 v = vsrc[k0];
    float dx = v.x - mxs, dy = v.y - mys;
    for (int k = k0; k < k1; ++k) {
        int kn = k + 1; if (kn == kv) kn = 0;
        float2 vn = vsrc[kn];
        float rx = vn.x - mxs, ry = vn.y - mys;
        v2f cross = { dy * rx - dx * ry, 0.0f };
        v2f dot   = { fmaf(dx, rx, dy * ry), 1.0f };
        acc += edge_term(cross, dot).x;
        dx = rx; dy = ry;
    }
    return acc;
}

__global__ __launch_bounds__(BLOCK)
void contour_mask_kernel(const float2* __restrict__ contour,
                         const int* __restrict__ size_ptr,
                         float* __restrict__ out,
                         int out_size, int in0_elems)
{
    __shared__ float2 verts[MAX_KV_LDS + 1];

    const int size     = *size_ptr;            // wave-uniform scalar load
    const int S2       = size * size;
    const int bn_total = out_size / S2;
    const int kv       = in0_elems / (bn_total * 2);

    const int tid  = threadIdx.x;
    const int PIX_PER_BLOCK = (BLOCK / SPLIT) * PPT;     // 128
    const int base = blockIdx.x * PIX_PER_BLOCK;

    const int bn0 = base / S2;                 // uniform (scalar) divide
    const int rem = base - bn0 * S2;
    const bool one_image = (rem + PIX_PER_BLOCK <= S2) &&
                           (base + PIX_PER_BLOCK <= out_size);
    const bool use_lds = (kv <= MAX_KV_LDS) && one_image;

    if (use_lds) {
        for (int i = tid; i < kv; i += BLOCK)
            verts[i] = contour[(size_t)bn0 * kv + i];
        if (tid == 0)
            verts[kv] = contour[(size_t)bn0 * kv];   // wraparound duplicate
    }
    __syncthreads();

    const int seg = tid & (SPLIT - 1);
    const int q   = (kv + SPLIT - 1) / SPLIT;  // edges per segment
    const int k0  = min(seg * q, kv);
    const int k1  = min(k0 + q, kv);
    const float inv_size = 1.0f / (float)size;
    const float INV2PI = 0.15915494309189535f;

    if (use_lds) {
        const int pi0 = rem / size;            // uniform
        const int pj0 = rem - pi0 * size;
        const int t   = (tid / SPLIT) * PPT;   // even local pixel offset

        int pjA = pj0 + t, piA = pi0;
        while (pjA >= size) { pjA -= size; ++piA; }
        int pjB = pjA + 1, piB = piA;
        if (pjB >= size) { pjB = 0; ++piB; }

        // mesh: ch0 = i/size, ch1 = j/size  (meshgrid 'ij')
        v2f mx2 = { piA * inv_size, piB * inv_size };
        v2f my2 = { pjA * inv_size, pjB * inv_size };

        v2f acc = winding_pk(verts, k0, k1, mx2, my2);
        acc.x += __shfl_xor(acc.x, 1, 64);
        acc.y += __shfl_xor(acc.y, 1, 64);
        acc.x += __shfl_xor(acc.x, 2, 64);
        acc.y += __shfl_xor(acc.y, 2, 64);

        if (seg == 0) {
            float2 res;
            res.x = fminf(fabsf(acc.x) * INV2PI, 1.0f);
            res.y = fminf(fabsf(acc.y) * INV2PI, 1.0f);
            *(float2*)(out + base + t) = res;   // coalesced 8B store
        }
    } else {
        #pragma unroll
        for (int px = 0; px < PPT; ++px) {
            const int pixel = base + (tid / SPLIT) * PPT + px;
            float a = 0.0f;
            if (pixel < out_size) {
                const int bn = pixel / S2;
                const int p  = pixel - bn * S2;
                const int pi = p / size;
                const int pj = p - pi * size;
                a = winding_scalar(contour + (size_t)bn * kv, kv, k0, k1,
                                   pi * inv_size, pj * inv_size);
            }
            a += __shfl_xor(a, 1, 64);
            a += __shfl_xor(a, 2, 64);
            if (pixel < out_size && seg == 0)
                out[pixel] = fminf(fabsf(a) * INV2PI, 1.0f);
        }
    }
}

extern "C" void kernel_launch(void* const* d_in, const int* in_sizes, int n_in,
                              void* d_out, int out_size, void* d_ws, size_t ws_size,
                              hipStream_t stream)
{
    const float2* contour  = (const float2*)d_in[0];
    const int*    size_ptr = (const int*)d_in[1];
    float*        out      = (float*)d_out;

    const int PIX_PER_BLOCK = (BLOCK / SPLIT) * PPT;   // 128 pixels per block
    const int blocks = (out_size + PIX_PER_BLOCK - 1) / PIX_PER_BLOCK;
    contour_mask_kernel<<<blocks, BLOCK, 0, stream>>>(
        contour, size_ptr, out, out_size, in_sizes[0]);
}